// Round 5
// baseline (16754.112 us; speedup 1.0000x reference)
//
#include <hip/hip_runtime.h>
#include <cstddef>

#define T_STEPS 1024
#define NB      64
#define DIN     128
#define HID     256

typedef unsigned short u16;
typedef __attribute__((ext_vector_type(8))) short short8;
typedef __attribute__((ext_vector_type(4))) float f32x4;

// ws byte offsets
#define WV_OFF   0u          // bf16 weights [2][64 nt][12 ks][64 lane][8] = 1,572,864 B
#define BIAS_OFF 1572864u    // float [2][1024]  (row n = j*4+q interleave)
#define XB_OFF   1581056u    // bf16 x [1024][64][128] = 16,777,216 B

#define OUT_MAIN (T_STEPS * NB * 2 * HID)
#define TAIL_H   OUT_MAIN
#define TAIL_C   (OUT_MAIN + 2 * NB * HID)

__device__ __forceinline__ u16 f2bf(float f) {
  unsigned u = __float_as_uint(f);
  return (u16)((u + 0x7fffu + ((u >> 16) & 1u)) >> 16);  // RNE
}
__device__ __forceinline__ float bf2f(u16 h) {
  return __uint_as_float(((unsigned)h) << 16);
}
__device__ __forceinline__ float sigm(float v) { return 1.f / (1.f + __expf(-v)); }
__device__ __forceinline__ float tanh_fast(float x) {
  float e = __expf(-2.f * fabsf(x));
  float r = (1.f - e) / (1.f + e);
  return x < 0.f ? -r : r;
}

__global__ void prep_kernel(const float* __restrict__ x,
                            const float* __restrict__ Wih_f, const float* __restrict__ Whh_f,
                            const float* __restrict__ bih_f, const float* __restrict__ bhh_f,
                            const float* __restrict__ Wih_r, const float* __restrict__ Whh_r,
                            const float* __restrict__ bih_r, const float* __restrict__ bhh_r,
                            u16* __restrict__ Wv, float* __restrict__ bias4,
                            u16* __restrict__ xb) {
  const int total = 786432 + 2048 + 8388608;
  for (int i = blockIdx.x * blockDim.x + threadIdx.x; i < total;
       i += gridDim.x * blockDim.x) {
    if (i < 786432) {
      int d  = i / 393216;
      int r  = i - d * 393216;
      int nt = r / 6144;
      int r2 = r - nt * 6144;
      int ks = r2 >> 9;
      int r3 = r2 & 511;
      int lq = r3 >> 3;
      int e  = r3 & 7;
      int n = nt * 16 + (lq & 15);
      int j = n >> 2, q = n & 3;
      int g = q * HID + j;                      // torch gate row
      int kk = (lq >> 4) * 8 + e;
      int k = (ks < 4) ? (ks * 32 + kk) : (DIN + (ks - 4) * 32 + kk);
      const float* Wih = d ? Wih_r : Wih_f;
      const float* Whh = d ? Whh_r : Whh_f;
      float v = (k < DIN) ? Wih[g * DIN + k] : Whh[g * HID + (k - DIN)];
      Wv[i] = f2bf(v);
    } else if (i < 786432 + 2048) {
      int r = i - 786432;
      int d = r >> 10, n = r & 1023;
      int j = n >> 2, q = n & 3;
      int g = q * HID + j;
      bias4[r] = d ? (bih_r[g] + bhh_r[g]) : (bih_f[g] + bhh_f[g]);
    } else {
      int r = i - (786432 + 2048);
      xb[r] = f2bf(x[r]);                       // [t][b][k]
    }
  }
}

#define MFMA __builtin_amdgcn_mfma_f32_16x16x32_bf16

#define LOADB(BUF, NTL) \
  _Pragma("unroll") for (int ks = 0; ks < 12; ++ks) BUF[ks] = Wq[lbase + ((NTL) * 12 + ks) * 64];

#define DO_NT(NTL, B) { \
  float bv = bias_r[NTL]; \
  f32x4 acc = {bv, bv, bv, bv}; \
  f32x4 acl = {0.f, 0.f, 0.f, 0.f}; \
  acc = MFMA(Ax0, *(const short8*)&B[0], acc, 0, 0, 0); \
  acc = MFMA(Ax1, *(const short8*)&B[1], acc, 0, 0, 0); \
  acc = MFMA(Ax2, *(const short8*)&B[2], acc, 0, 0, 0); \
  acc = MFMA(Ax3, *(const short8*)&B[3], acc, 0, 0, 0); \
  acc = MFMA(Ah0, *(const short8*)&B[4],  acc, 0, 0, 0); \
  acl = MFMA(Al0, *(const short8*)&B[4],  acl, 0, 0, 0); \
  acc = MFMA(Ah1, *(const short8*)&B[5],  acc, 0, 0, 0); \
  acl = MFMA(Al1, *(const short8*)&B[5],  acl, 0, 0, 0); \
  acc = MFMA(Ah2, *(const short8*)&B[6],  acc, 0, 0, 0); \
  acl = MFMA(Al2, *(const short8*)&B[6],  acl, 0, 0, 0); \
  acc = MFMA(Ah3, *(const short8*)&B[7],  acc, 0, 0, 0); \
  acl = MFMA(Al3, *(const short8*)&B[7],  acl, 0, 0, 0); \
  acc = MFMA(Ah4, *(const short8*)&B[8],  acc, 0, 0, 0); \
  acl = MFMA(Al4, *(const short8*)&B[8],  acl, 0, 0, 0); \
  acc = MFMA(Ah5, *(const short8*)&B[9],  acc, 0, 0, 0); \
  acl = MFMA(Al5, *(const short8*)&B[9],  acl, 0, 0, 0); \
  acc = MFMA(Ah6, *(const short8*)&B[10], acc, 0, 0, 0); \
  acl = MFMA(Al6, *(const short8*)&B[10], acl, 0, 0, 0); \
  acc = MFMA(Ah7, *(const short8*)&B[11], acc, 0, 0, 0); \
  acl = MFMA(Al7, *(const short8*)&B[11], acl, 0, 0, 0); \
  acc = acc + acl; \
  if (l < 32) { \
    int n = (w * 8 + (NTL)) * 16 + (l & 15); \
    int m0 = (l >> 4) * 4; \
    gl[m0 + 0][n] = acc[0]; gl[m0 + 1][n] = acc[1]; \
    gl[m0 + 2][n] = acc[2]; gl[m0 + 3][n] = acc[3]; } \
}

// 16 WGs x 512 threads. WG -> (d = wg&1, btile = wg>>1). Fully self-contained
// recurrence: h/c never leave the CU. Weights streamed from L2 each step.
__global__ __launch_bounds__(512, 1) void lstm_onewg(
    const u16* __restrict__ Wv, const float* __restrict__ bias4,
    const u16* __restrict__ xb, const float* __restrict__ hx,
    const float* __restrict__ cx, float* __restrict__ out) {
  __shared__ __align__(16) u16 in_[16][648];    // rows 0-7: x[0:128)|h_hi[128:384)|h_lo[384:640); rows 8-15 zero
  __shared__ __align__(16) float gl[8][1032];   // [batch][gate row n]

  const int tid = threadIdx.x;
  const int d = blockIdx.x & 1, btile = blockIdx.x >> 1;
  const int b0 = btile * 8;
  const int w = tid >> 6, l = tid & 63;

  // zero A rows 8..15
  { unsigned* z = (unsigned*)&in_[8][0];
    for (int i = tid; i < 2592; i += 512) z[i] = 0u; }

  // stage x(t0): row w, 2 bf16 per thread
  { int t0 = d ? (T_STEPS - 1) : 0;
    *(unsigned*)&in_[w][l * 2] =
        *(const unsigned*)&xb[((size_t)t0 * NB + b0 + w) * DIN + l * 2]; }

  // elementwise ownership: (eb, ej): cells j = ej + 64*cc
  const int eb = tid & 7, ej = tid >> 3;
  float cr[4];
#pragma unroll
  for (int cc = 0; cc < 4; ++cc) {
    int j = ej + 64 * cc;
    float v = hx[((size_t)d * NB + b0 + eb) * HID + j];
    u16 hh = f2bf(v), hl = f2bf(v - bf2f(hh));
    in_[eb][128 + j] = hh;
    in_[eb][384 + j] = hl;
    cr[cc] = cx[((size_t)d * NB + b0 + eb) * HID + j];
  }

  float bias_r[8];
#pragma unroll
  for (int ntl = 0; ntl < 8; ++ntl)
    bias_r[ntl] = bias4[d * 1024 + (w * 8 + ntl) * 16 + (l & 15)];

  const uint4* Wq = (const uint4*)(Wv + (size_t)d * 393216);
  const int lbase = w * 6144 + l;

  __syncthreads();

  for (int s = 0; s < T_STEPS; ++s) {
    const int t = d ? (T_STEPS - 1 - s) : s;

    // issue first B-tile loads (L2), then x prefetch, then A ds_reads
    uint4 Ba[12], Bb[12];
    LOADB(Ba, 0)
    unsigned xv = 0;
    if (s < T_STEPS - 1) {
      int tn = d ? (T_STEPS - 2 - s) : (s + 1);
      xv = *(const unsigned*)&xb[((size_t)tn * NB + b0 + w) * DIN + l * 2];
    }
    const u16* arow = &in_[l & 15][(l >> 4) * 8];
    short8 Ax0 = *(const short8*)(arow);
    short8 Ax1 = *(const short8*)(arow + 32);
    short8 Ax2 = *(const short8*)(arow + 64);
    short8 Ax3 = *(const short8*)(arow + 96);
    short8 Ah0 = *(const short8*)(arow + 128);
    short8 Ah1 = *(const short8*)(arow + 160);
    short8 Ah2 = *(const short8*)(arow + 192);
    short8 Ah3 = *(const short8*)(arow + 224);
    short8 Ah4 = *(const short8*)(arow + 256);
    short8 Ah5 = *(const short8*)(arow + 288);
    short8 Ah6 = *(const short8*)(arow + 320);
    short8 Ah7 = *(const short8*)(arow + 352);
    short8 Al0 = *(const short8*)(arow + 384);
    short8 Al1 = *(const short8*)(arow + 416);
    short8 Al2 = *(const short8*)(arow + 448);
    short8 Al3 = *(const short8*)(arow + 480);
    short8 Al4 = *(const short8*)(arow + 512);
    short8 Al5 = *(const short8*)(arow + 544);
    short8 Al6 = *(const short8*)(arow + 576);
    short8 Al7 = *(const short8*)(arow + 608);

    // (B) all waves done reading in_ -> x region may be overwritten later.
    // raw barrier: do NOT drain vmcnt (B prefetch + xv stay in flight)
    asm volatile("s_waitcnt lgkmcnt(0)" ::: "memory");
    __builtin_amdgcn_s_barrier();

    LOADB(Bb, 1) DO_NT(0, Ba)
    LOADB(Ba, 2) DO_NT(1, Bb)
    LOADB(Bb, 3) DO_NT(2, Ba)
    LOADB(Ba, 4) DO_NT(3, Bb)
    LOADB(Bb, 5) DO_NT(4, Ba)
    LOADB(Ba, 6) DO_NT(5, Bb)
    LOADB(Bb, 7) DO_NT(6, Ba)
    DO_NT(7, Bb)

    // park next x into LDS (waits vmcnt for xv only)
    if (s < T_STEPS - 1) *(unsigned*)&in_[w][l * 2] = xv;

    // (E) gates published
    asm volatile("s_waitcnt lgkmcnt(0)" ::: "memory");
    __builtin_amdgcn_s_barrier();

#pragma unroll
    for (int cc = 0; cc < 4; ++cc) {
      int j = ej + 64 * cc;
      f32x4 g4 = *(const f32x4*)&gl[eb][4 * j];
      float ii = sigm(g4[0]), ff = sigm(g4[1]);
      float gg = tanh_fast(g4[2]), oo = sigm(g4[3]);
      float c = ff * cr[cc] + ii * gg;
      cr[cc] = c;
      float h = oo * tanh_fast(c);
      u16 hh = f2bf(h), hl = f2bf(h - bf2f(hh));
      in_[eb][128 + j] = hh;
      in_[eb][384 + j] = hl;
      out[((size_t)t * NB + b0 + eb) * (2 * HID) + d * HID + j] = h;
      if (s == T_STEPS - 1) {
        out[TAIL_H + ((size_t)d * NB + b0 + eb) * HID + j] = h;
        out[TAIL_C + ((size_t)d * NB + b0 + eb) * HID + j] = c;
      }
    }

    // (G) new h visible to next step's A reads
    asm volatile("s_waitcnt lgkmcnt(0)" ::: "memory");
    __builtin_amdgcn_s_barrier();
  }
}

extern "C" void kernel_launch(void* const* d_in, const int* in_sizes, int n_in,
                              void* d_out, int out_size, void* d_ws, size_t ws_size,
                              hipStream_t stream) {
  const float* x     = (const float*)d_in[0];
  const float* hx    = (const float*)d_in[1];
  const float* cx    = (const float*)d_in[2];
  const float* Wih_f = (const float*)d_in[3];
  const float* Whh_f = (const float*)d_in[4];
  const float* bih_f = (const float*)d_in[5];
  const float* bhh_f = (const float*)d_in[6];
  const float* Wih_r = (const float*)d_in[7];
  const float* Whh_r = (const float*)d_in[8];
  const float* bih_r = (const float*)d_in[9];
  const float* bhh_r = (const float*)d_in[10];
  float* out = (float*)d_out;

  u16* Wv      = (u16*)((char*)d_ws + WV_OFF);
  float* bias4 = (float*)((char*)d_ws + BIAS_OFF);
  u16* xb      = (u16*)((char*)d_ws + XB_OFF);

  hipLaunchKernelGGL(prep_kernel, dim3(2048), dim3(256), 0, stream,
                     x, Wih_f, Whh_f, bih_f, bhh_f, Wih_r, Whh_r, bih_r, bhh_r,
                     Wv, bias4, xb);
  hipLaunchKernelGGL(lstm_onewg, dim3(16), dim3(512), 0, stream,
                     Wv, bias4, xb, hx, cx, out);
}

// Round 6
// 3201.328 us; speedup vs baseline: 5.2335x; 5.2335x over previous
//
#include <hip/hip_runtime.h>
#include <cstddef>

#define T_STEPS 1024
#define NB      64
#define DIN     128
#define HID     256

typedef unsigned short u16;
typedef unsigned int u32;
typedef unsigned long long u64;
typedef __attribute__((ext_vector_type(8))) short short8;
typedef __attribute__((ext_vector_type(4))) float f32x4;

// ws byte offsets
#define WG_OFF   0u           // bf16 [2][8 wgi][128 nloc][384 k] = 1,572,864 B
#define BIAS_OFF 1572864u     // f32 [2][1024] (row n = j*4+q)
#define XB_OFF   1581056u     // bf16 x [1024][64][128] = 16,777,216 B
#define HB_OFF   18358272u    // u32 hbuf [2 par][16 grp][8 wgi][8 b][32 j] = 262,144 B
#define FL_OFF   18620416u    // u32 flags [1025][16 grp][8 wgi] = 524,800 B

#define OUT_MAIN (T_STEPS * NB * 2 * HID)
#define TAIL_H   OUT_MAIN
#define TAIL_C   (OUT_MAIN + 2 * NB * HID)

__device__ __forceinline__ u16 f2bf(float f) {
  unsigned u = __float_as_uint(f);
  return (u16)((u + 0x7fffu + ((u >> 16) & 1u)) >> 16);  // RNE
}
__device__ __forceinline__ float bf2f(u16 h) {
  return __uint_as_float(((unsigned)h) << 16);
}
__device__ __forceinline__ float sigm(float v) { return 1.f / (1.f + __expf(-v)); }
__device__ __forceinline__ float tanh_fast(float x) {
  float e = __expf(-2.f * fabsf(x));
  float r = (1.f - e) / (1.f + e);
  return x < 0.f ? -r : r;
}

__global__ void prep_kernel(const float* __restrict__ x,
                            const float* __restrict__ Wih_f, const float* __restrict__ Whh_f,
                            const float* __restrict__ bih_f, const float* __restrict__ bhh_f,
                            const float* __restrict__ Wih_r, const float* __restrict__ Whh_r,
                            const float* __restrict__ bih_r, const float* __restrict__ bhh_r,
                            const float* __restrict__ hx,
                            u16* __restrict__ Wg, float* __restrict__ bias4,
                            u16* __restrict__ xb, u32* __restrict__ hbuf,
                            u32* __restrict__ flags) {
  // segments: W 786432 | bias 2048 | xb 8388608 | hbuf-init 32768 | flags 131200
  const int total = 786432 + 2048 + 8388608 + 32768 + 131200;
  for (int i = blockIdx.x * blockDim.x + threadIdx.x; i < total;
       i += gridDim.x * blockDim.x) {
    if (i < 786432) {
      int d  = i / 393216;
      int r  = i - d * 393216;
      int wgi  = r / 49152;
      int r2   = r - wgi * 49152;
      int nloc = r2 / 384;
      int k    = r2 - nloc * 384;
      int j = wgi * 32 + (nloc >> 2);
      int q = nloc & 3;
      int g = q * HID + j;                      // torch gate row
      const float* Wih = d ? Wih_r : Wih_f;
      const float* Whh = d ? Whh_r : Whh_f;
      float v = (k < DIN) ? Wih[g * DIN + k] : Whh[g * HID + (k - DIN)];
      Wg[i] = f2bf(v);
    } else if (i < 786432 + 2048) {
      int r = i - 786432;
      int d = r >> 10, n = r & 1023;
      int j = n >> 2, q = n & 3;
      int g = q * HID + j;
      bias4[r] = d ? (bih_r[g] + bhh_r[g]) : (bih_f[g] + bhh_f[g]);
    } else if (i < 786432 + 2048 + 8388608) {
      int r = i - (786432 + 2048);
      xb[r] = f2bf(x[r]);                       // [t][b][k]
    } else if (i < 786432 + 2048 + 8388608 + 32768) {
      int r = i - (786432 + 2048 + 8388608);    // (d*64+b)*256 + j
      int d = r >> 14, rem = r & 16383;
      int b = rem >> 8, j = rem & 255;
      float v = hx[r];
      u16 hh = f2bf(v), hl = f2bf(v - bf2f(hh));
      int grp = d * 8 + (b >> 3), wgi = j >> 5;
      int idx = (((1 * 16 + grp) * 8) + wgi) * 256 + (b & 7) * 32 + (j & 31);
      hbuf[idx] = (u32)hh | ((u32)hl << 16);    // parity-1 slot = initial h
    } else {
      int r = i - (786432 + 2048 + 8388608 + 32768);
      flags[r] = (r < 128) ? 1u : 0u;           // row 0: initial h ready
    }
  }
}

#define MFMA __builtin_amdgcn_mfma_f32_16x16x32_bf16

// one 16-gate-row n-tile: full K (x:4 blocks; h hi/lo: 8 blocks sharing B)
#define DO_NT(NTL, BV) { \
  const u16* wr = wl + (size_t)((NTL) * 16 + (l & 15)) * 392 + ((l >> 4) * 8); \
  f32x4 acc = {BV, BV, BV, BV}; \
  f32x4 acl = {0.f, 0.f, 0.f, 0.f}; \
  short8 B0 = *(const short8*)(wr + 0); \
  short8 B1 = *(const short8*)(wr + 32); \
  short8 B2 = *(const short8*)(wr + 64); \
  short8 B3 = *(const short8*)(wr + 96); \
  acc = MFMA(Ax0, B0, acc, 0, 0, 0); \
  acc = MFMA(Ax1, B1, acc, 0, 0, 0); \
  acc = MFMA(Ax2, B2, acc, 0, 0, 0); \
  acc = MFMA(Ax3, B3, acc, 0, 0, 0); \
  short8 H0 = *(const short8*)(wr + 128 + 0); \
  short8 H1 = *(const short8*)(wr + 128 + 32); \
  short8 H2 = *(const short8*)(wr + 128 + 64); \
  short8 H3 = *(const short8*)(wr + 128 + 96); \
  acc = MFMA(Ah0, H0, acc, 0, 0, 0);  acl = MFMA(Al0, H0, acl, 0, 0, 0); \
  acc = MFMA(Ah1, H1, acc, 0, 0, 0);  acl = MFMA(Al1, H1, acl, 0, 0, 0); \
  acc = MFMA(Ah2, H2, acc, 0, 0, 0);  acl = MFMA(Al2, H2, acl, 0, 0, 0); \
  acc = MFMA(Ah3, H3, acc, 0, 0, 0);  acl = MFMA(Al3, H3, acl, 0, 0, 0); \
  short8 H4 = *(const short8*)(wr + 128 + 128); \
  short8 H5 = *(const short8*)(wr + 128 + 160); \
  short8 H6 = *(const short8*)(wr + 128 + 192); \
  short8 H7 = *(const short8*)(wr + 128 + 224); \
  acc = MFMA(Ah4, H4, acc, 0, 0, 0);  acl = MFMA(Al4, H4, acl, 0, 0, 0); \
  acc = MFMA(Ah5, H5, acc, 0, 0, 0);  acl = MFMA(Al5, H5, acl, 0, 0, 0); \
  acc = MFMA(Ah6, H6, acc, 0, 0, 0);  acl = MFMA(Al6, H6, acl, 0, 0, 0); \
  acc = MFMA(Ah7, H7, acc, 0, 0, 0);  acl = MFMA(Al7, H7, acl, 0, 0, 0); \
  acc = acc + acl; \
  if (l < 32) { \
    int n = (NTL) * 16 + (l & 15); \
    int m0 = (l >> 4) * 4; \
    gl[(m0 + 0) * 132 + n] = acc[0]; gl[(m0 + 1) * 132 + n] = acc[1]; \
    gl[(m0 + 2) * 132 + n] = acc[2]; gl[(m0 + 3) * 132 + n] = acc[3]; } \
}

// 128 WGs x 256 thr. blockIdx = grp*8 + wgi; grp = d*8 + btile.
// Per WG: 128 gate rows (j in [wgi*32,wgi*32+32)), 8 batches, weights in LDS.
// Exchange: step-indexed flags + parity-2 packed h chunks via LLC; no RMW.
__global__ __launch_bounds__(256, 1) void lstm_grp(
    const u16* __restrict__ Wg, const float* __restrict__ bias4,
    const u16* __restrict__ xb, const float* __restrict__ cx,
    u32* __restrict__ hbuf, u32* __restrict__ flags,
    float* __restrict__ out) {
  extern __shared__ char smem[];
  u16* wl   = (u16*)smem;                 // [128][392]  100,352 B
  u16* inb  = (u16*)(smem + 100352);      // [16][648]   x|h_hi|h_lo, rows 8-15 zero
  float* gl = (float*)(smem + 121088);    // [8][132]

  const int tid = threadIdx.x;
  const int grp = blockIdx.x >> 3, wgi = blockIdx.x & 7;
  const int d = grp >> 3, btile = grp & 7;
  const int b0 = btile * 8;
  const int w = tid >> 6, l = tid & 63;

  // one-time: weight slice -> LDS (stride 392 u16 = 196 u32, ~2-way banks)
  {
    const u32* src = (const u32*)(Wg + (size_t)(d * 8 + wgi) * 49152);
    u32* dst = (u32*)wl;
    for (int iu = tid; iu < 128 * 192; iu += 256) {
      int r = iu / 192, c = iu - r * 192;
      dst[r * 196 + c] = src[iu];
    }
  }
  // zero A rows 8..15 (full rows: x + h regions)
  { u32* z = (u32*)(inb + 8 * 648);
    for (int i2 = tid; i2 < 2592; i2 += 256) z[i2] = 0u; }

  // elementwise identity: 1 cell per thread
  const int eb = tid >> 5, ej = tid & 31;
  const int jglob = wgi * 32 + ej;
  float c_reg = cx[((size_t)d * NB + b0 + eb) * HID + jglob];
  const float bv0 = bias4[d * 1024 + wgi * 128 + (w * 2 + 0) * 16 + (l & 15)];
  const float bv1 = bias4[d * 1024 + wgi * 128 + (w * 2 + 1) * 16 + (l & 15)];

  // prologue x(t0) prefetch
  u64 xv;
  { int t0 = d ? (T_STEPS - 1) : 0;
    xv = *(const u64*)&xb[((size_t)t0 * NB + b0 + (tid >> 5)) * DIN + (tid & 31) * 4]; }
  __syncthreads();

  for (int s = 0; s < T_STEPS; ++s) {
    const int t  = d ? (T_STEPS - 1 - s) : s;
    const int pr = (s & 1) ^ 1;     // parity holding h(s-1)
    const int ps = s & 1;           // parity we write h(s) into

    // ---- parking phase: x + remote h chunks ----
    *(u64*)&inb[(size_t)(tid >> 5) * 648 + (tid & 31) * 4] = xv;
    {
      int r = tid >> 5, u = tid & 31;
      if (s == 0 || r != wgi) {     // own chunk parked at elementwise (s>0)
        const u32* flg = flags + (size_t)s * 128 + grp * 8 + r;
        while (__hip_atomic_load(flg, __ATOMIC_RELAXED, __HIP_MEMORY_SCOPE_AGENT) == 0u)
          __builtin_amdgcn_s_sleep(1);
        __builtin_amdgcn_sched_barrier(0);
        const u64* cb_ = (const u64*)(hbuf + (((size_t)pr * 16 + grp) * 8 + r) * 256 + u * 8);
        u64 v0 = __hip_atomic_load(cb_ + 0, __ATOMIC_RELAXED, __HIP_MEMORY_SCOPE_AGENT);
        u64 v1 = __hip_atomic_load(cb_ + 1, __ATOMIC_RELAXED, __HIP_MEMORY_SCOPE_AGENT);
        u64 v2 = __hip_atomic_load(cb_ + 2, __ATOMIC_RELAXED, __HIP_MEMORY_SCOPE_AGENT);
        u64 v3 = __hip_atomic_load(cb_ + 3, __ATOMIC_RELAXED, __HIP_MEMORY_SCOPE_AGENT);
        u32 pv[8] = {(u32)v0, (u32)(v0 >> 32), (u32)v1, (u32)(v1 >> 32),
                     (u32)v2, (u32)(v2 >> 32), (u32)v3, (u32)(v3 >> 32)};
        short8 H, L;
#pragma unroll
        for (int e = 0; e < 8; ++e) {
          H[e] = (short)(pv[e] & 0xffffu);
          L[e] = (short)(pv[e] >> 16);
        }
        int b = u >> 2, j0l = r * 32 + (u & 3) * 8;
        *(short8*)&inb[(size_t)b * 648 + 128 + j0l] = H;
        *(short8*)&inb[(size_t)b * 648 + 384 + j0l] = L;
      }
    }
    asm volatile("s_waitcnt lgkmcnt(0)" ::: "memory");
    __builtin_amdgcn_s_barrier();

    // ---- A-fragment reads + next-x prefetch ----
    const u16* arow = inb + (size_t)(l & 15) * 648 + ((l >> 4) * 8);
    short8 Ax0 = *(const short8*)(arow);
    short8 Ax1 = *(const short8*)(arow + 32);
    short8 Ax2 = *(const short8*)(arow + 64);
    short8 Ax3 = *(const short8*)(arow + 96);
    short8 Ah0 = *(const short8*)(arow + 128);
    short8 Ah1 = *(const short8*)(arow + 160);
    short8 Ah2 = *(const short8*)(arow + 192);
    short8 Ah3 = *(const short8*)(arow + 224);
    short8 Ah4 = *(const short8*)(arow + 256);
    short8 Ah5 = *(const short8*)(arow + 288);
    short8 Ah6 = *(const short8*)(arow + 320);
    short8 Ah7 = *(const short8*)(arow + 352);
    short8 Al0 = *(const short8*)(arow + 384);
    short8 Al1 = *(const short8*)(arow + 416);
    short8 Al2 = *(const short8*)(arow + 448);
    short8 Al3 = *(const short8*)(arow + 480);
    short8 Al4 = *(const short8*)(arow + 512);
    short8 Al5 = *(const short8*)(arow + 544);
    short8 Al6 = *(const short8*)(arow + 576);
    short8 Al7 = *(const short8*)(arow + 608);
    if (s < T_STEPS - 1) {
      int tn = d ? (T_STEPS - 2 - s) : (s + 1);
      xv = *(const u64*)&xb[((size_t)tn * NB + b0 + (tid >> 5)) * DIN + (tid & 31) * 4];
    }

    // ---- MFMA: 2 n-tiles per wave ----
    DO_NT(w * 2 + 0, bv0)
    DO_NT(w * 2 + 1, bv1)
    asm volatile("s_waitcnt lgkmcnt(0)" ::: "memory");
    __builtin_amdgcn_s_barrier();

    // ---- elementwise ----
    {
      f32x4 g4 = *(const f32x4*)&gl[(size_t)eb * 132 + 4 * ej];
      float ii = sigm(g4[0]), ff = sigm(g4[1]);
      float gg = tanh_fast(g4[2]), oo = sigm(g4[3]);
      float c = ff * c_reg + ii * gg;
      c_reg = c;
      float h = oo * tanh_fast(c);
      u16 hh = f2bf(h), hl = f2bf(h - bf2f(hh));
      inb[(size_t)eb * 648 + 128 + jglob] = hh;   // own h direct to LDS
      inb[(size_t)eb * 648 + 384 + jglob] = hl;
      __hip_atomic_store(hbuf + (((size_t)ps * 16 + grp) * 8 + wgi) * 256 + eb * 32 + ej,
                         (u32)hh | ((u32)hl << 16),
                         __ATOMIC_RELAXED, __HIP_MEMORY_SCOPE_AGENT);
      out[((size_t)t * NB + b0 + eb) * (2 * HID) + d * HID + jglob] = h;
      if (s == T_STEPS - 1) {
        out[TAIL_H + ((size_t)d * NB + b0 + eb) * HID + jglob] = h;
        out[TAIL_C + ((size_t)d * NB + b0 + eb) * HID + jglob] = c_reg;
      }
    }
    // all h stores at LLC before flag publish
    asm volatile("s_waitcnt vmcnt(0)" ::: "memory");
    __builtin_amdgcn_s_barrier();
    if (tid == 0 && s < T_STEPS - 1)
      __hip_atomic_store(flags + (size_t)(s + 1) * 128 + grp * 8 + wgi, 1u,
                         __ATOMIC_RELAXED, __HIP_MEMORY_SCOPE_AGENT);
  }
}

extern "C" void kernel_launch(void* const* d_in, const int* in_sizes, int n_in,
                              void* d_out, int out_size, void* d_ws, size_t ws_size,
                              hipStream_t stream) {
  const float* x     = (const float*)d_in[0];
  const float* hx    = (const float*)d_in[1];
  const float* cx    = (const float*)d_in[2];
  const float* Wih_f = (const float*)d_in[3];
  const float* Whh_f = (const float*)d_in[4];
  const float* bih_f = (const float*)d_in[5];
  const float* bhh_f = (const float*)d_in[6];
  const float* Wih_r = (const float*)d_in[7];
  const float* Whh_r = (const float*)d_in[8];
  const float* bih_r = (const float*)d_in[9];
  const float* bhh_r = (const float*)d_in[10];
  float* out = (float*)d_out;

  u16* Wg      = (u16*)((char*)d_ws + WG_OFF);
  float* bias4 = (float*)((char*)d_ws + BIAS_OFF);
  u16* xb      = (u16*)((char*)d_ws + XB_OFF);
  u32* hbuf    = (u32*)((char*)d_ws + HB_OFF);
  u32* flags   = (u32*)((char*)d_ws + FL_OFF);

  hipFuncSetAttribute((const void*)lstm_grp,
                      hipFuncAttributeMaxDynamicSharedMemorySize, 125312);

  hipLaunchKernelGGL(prep_kernel, dim3(2048), dim3(256), 0, stream,
                     x, Wih_f, Whh_f, bih_f, bhh_f, Wih_r, Whh_r, bih_r, bhh_r,
                     hx, Wg, bias4, xb, hbuf, flags);
  hipLaunchKernelGGL(lstm_grp, dim3(128), dim3(256), 125312, stream,
                     Wg, bias4, xb, cx, hbuf, flags, out);
}